// Round 14
// baseline (314.234 us; speedup 1.0000x reference)
//
#include <hip/hip_runtime.h>

#define N_NODES 100000
#define HID 64
#define N_EDGES 1600000
#define NB 391                 // ceil(N_NODES / 256) buckets of 256 nodes
#define C_EPB 6400             // edges per block in bucket_scatter (250 blocks)
#define G_GATHER 6250          // N_NODES*16/256 gather blocks (exact)

typedef __attribute__((ext_vector_type(8))) short bf16x8;
typedef __attribute__((ext_vector_type(4))) float f32x4;

// ---- bf16 helpers (manual, RNE) ------------------------------------------
__device__ __forceinline__ unsigned short f2bf(float f) {
    unsigned u = __float_as_uint(f);
    u = (u + 0x7FFFu + ((u >> 16) & 1u)) >> 16;
    return (unsigned short)u;
}
__device__ __forceinline__ float bflo(unsigned w) { return __uint_as_float(w << 16); }
__device__ __forceinline__ float bfhi(unsigned w) { return __uint_as_float(w & 0xFFFF0000u); }

// ---------------------------------------------------------------- gather + hist + wprep
// Role-split grid:
//   [0, G_GATHER)            : xh = bf16(emb[node_id])
//   [G_GATHER, G_GATHER+256) : global bucket histogram (dst>>8)
//   last 2 blocks            : convert layer-1/2 weights to B-frag bf16 buffers
__global__ void gather_hist_kernel(const float* __restrict__ emb,
                                   const int* __restrict__ nid,
                                   unsigned short* __restrict__ xh,
                                   const int* __restrict__ dst,
                                   int* __restrict__ bhist,
                                   const float* __restrict__ Wl1,
                                   const float* __restrict__ Wr1,
                                   const float* __restrict__ Wl2,
                                   const float* __restrict__ Wr2,
                                   unsigned short* __restrict__ wf1,
                                   unsigned short* __restrict__ wf2) {
    __shared__ int h[NB];
    if (blockIdx.x < G_GATHER) {
        int i = blockIdx.x * blockDim.x + threadIdx.x;   // < 1.6M exactly
        int row = i >> 4;
        int c   = i & 15;
        int s   = nid[row];
        float4 v = reinterpret_cast<const float4*>(emb)[(size_t)s * 16 + c];
        uint2 p;
        p.x = (unsigned)f2bf(v.x) | ((unsigned)f2bf(v.y) << 16);
        p.y = (unsigned)f2bf(v.z) | ((unsigned)f2bf(v.w) << 16);
        reinterpret_cast<uint2*>(xh)[(size_t)row * 16 + c] = p;
    } else if (blockIdx.x < G_GATHER + 256) {
        int hb = blockIdx.x - G_GATHER;
        for (int i = threadIdx.x; i < NB; i += blockDim.x) h[i] = 0;
        __syncthreads();
        int nt = 256 * blockDim.x;
        const int4* d4 = (const int4*)dst;
        for (int q = hb * blockDim.x + threadIdx.x; q < N_EDGES / 4; q += nt) {
            int4 v = d4[q];
            atomicAdd(&h[v.x >> 8], 1);
            atomicAdd(&h[v.y >> 8], 1);
            atomicAdd(&h[v.z >> 8], 1);
            atomicAdd(&h[v.w >> 8], 1);
        }
        __syncthreads();
        for (int i = threadIdx.x; i < NB; i += blockDim.x)
            if (h[i]) atomicAdd(&bhist[i], h[i]);
    } else {
        // weight frag prep: wf[((mat*2+ks)*4+ct)*512 + lane*8 + j]
        //   = bf16(W_mat[(ct*16+m)*64 + ks*32 + quad*8 + j]), lane=(m,quad)
        int layer = blockIdx.x - (G_GATHER + 256);   // 0 or 1
        const float* Wl = layer ? Wl2 : Wl1;
        const float* Wr = layer ? Wr2 : Wr1;
        unsigned short* wf = layer ? wf2 : wf1;
        for (int f = threadIdx.x; f < 8192; f += 256) {
            int mat = f >> 12;
            int ks  = (f >> 11) & 1;
            int ct  = (f >> 9) & 3;
            int ln  = (f >> 3) & 63;
            int j   = f & 7;
            int m = ln & 15, quad = ln >> 4;
            const float* W = mat ? Wr : Wl;
            wf[f] = f2bf(W[(ct * 16 + m) * HID + ks * 32 + quad * 8 + j]);
        }
    }
}

// ---------------------------------------------------------------- CSR build, pass B
__global__ void bucket_scan(const int* __restrict__ bhist,
                            int* __restrict__ boff,
                            int* __restrict__ bcursor) {
    __shared__ int s[512];
    int v = (threadIdx.x < NB) ? bhist[threadIdx.x] : 0;
    s[threadIdx.x] = v;
    __syncthreads();
    for (int off = 1; off < 512; off <<= 1) {
        int t = (threadIdx.x >= off) ? s[threadIdx.x - off] : 0;
        __syncthreads();
        s[threadIdx.x] += t;
        __syncthreads();
    }
    if (threadIdx.x < NB) {
        int ex = s[threadIdx.x] - v;
        boff[threadIdx.x] = ex;
        bcursor[threadIdx.x] = ex;
    }
}

// ---------------------------------------------------------------- CSR build, pass C
__global__ void bucket_scatter(const int* __restrict__ src,
                               const int* __restrict__ dst,
                               int* __restrict__ bcursor,
                               int* __restrict__ pairs) {
    __shared__ int h[NB];
    __shared__ int base[NB];
    for (int i = threadIdx.x; i < NB; i += blockDim.x) h[i] = 0;
    __syncthreads();
    int q0 = blockIdx.x * (C_EPB / 4);
    int q1 = q0 + (C_EPB / 4);
    const int4* d4 = (const int4*)dst;
    const int4* s4 = (const int4*)src;
    for (int q = q0 + threadIdx.x; q < q1; q += blockDim.x) {
        int4 v = d4[q];
        atomicAdd(&h[v.x >> 8], 1);
        atomicAdd(&h[v.y >> 8], 1);
        atomicAdd(&h[v.z >> 8], 1);
        atomicAdd(&h[v.w >> 8], 1);
    }
    __syncthreads();
    for (int i = threadIdx.x; i < NB; i += blockDim.x) {
        int c = h[i];
        base[i] = c ? atomicAdd(&bcursor[i], c) : 0;
    }
    __syncthreads();
    for (int i = threadIdx.x; i < NB; i += blockDim.x) h[i] = 0;
    __syncthreads();
    for (int q = q0 + threadIdx.x; q < q1; q += blockDim.x) {
        int4 d = d4[q];
        int4 s = s4[q];
        int b, slot;
        b = d.x >> 8; slot = base[b] + atomicAdd(&h[b], 1); pairs[slot] = (s.x << 8) | (d.x & 255);
        b = d.y >> 8; slot = base[b] + atomicAdd(&h[b], 1); pairs[slot] = (s.y << 8) | (d.y & 255);
        b = d.z >> 8; slot = base[b] + atomicAdd(&h[b], 1); pairs[slot] = (s.z << 8) | (d.z & 255);
        b = d.w >> 8; slot = base[b] + atomicAdd(&h[b], 1); pairs[slot] = (s.w << 8) | (d.w & 255);
    }
}

// ---------------------------------------------------------------- CSR build, pass D
__global__ void bucket_csr(const int* __restrict__ pairs,
                           const int* __restrict__ boff,
                           const int* __restrict__ bcursor,
                           int* __restrict__ row_start,
                           int* __restrict__ adj) {
    __shared__ int cnt[256];
    __shared__ int sc[256];
    int b = blockIdx.x;
    int node0 = b << 8;
    int p0 = boff[b];
    int p1 = bcursor[b];           // after pass C, bcursor[b] = end of bucket b
    int t = threadIdx.x;
    cnt[t] = 0;
    __syncthreads();
    for (int p = p0 + t; p < p1; p += 256)
        atomicAdd(&cnt[pairs[p] & 255], 1);
    __syncthreads();
    int v = cnt[t];
    sc[t] = v;
    __syncthreads();
    for (int off = 1; off < 256; off <<= 1) {
        int u = (t >= off) ? sc[t - off] : 0;
        __syncthreads();
        sc[t] += u;
        __syncthreads();
    }
    sc[t] = p0 + sc[t] - v;        // exclusive scan + bucket base = row_start
    __syncthreads();
    int node = node0 + t;
    if (node <= N_NODES) row_start[node] = sc[t];
    __syncthreads();               // row_start read before atomics mutate sc
    for (int p = p0 + t; p < p1; p += 256) {
        int pr = pairs[p];
        int slot = atomicAdd(&sc[pr & 255], 1);
        adj[slot] = ((unsigned)pr) >> 8;
    }
}

// ---------------------------------------------------------------- aggregation (dual-row)
// Each wave aggregates TWO consecutive rows with interleaved loads: the dual
// main loop issues 8 load instructions (4/row x 8B x 4 slots) before any
// consume -> 32 rows in flight (edge_dot-equivalent MLP; single-row agg is
// degree-capped at 16). Tails use the single-row path. Consecutive rows have
// adjacent adj ranges (L1-friendly).
__global__ void agg_kernel(const int* __restrict__ row_start,
                           const int* __restrict__ adj,
                           const unsigned short* __restrict__ xh,
                           unsigned short* __restrict__ M) {
    int lane = threadIdx.x & 63;
    int slot = lane >> 4;               // 0..3  edge slot
    int c    = lane & 15;               // uint2 column (features 4c..4c+3)
    int wpb = blockDim.x >> 6;
    int wid = blockIdx.x * wpb + (threadIdx.x >> 6);
    int stride = gridDim.x * wpb;
    const uint2* xw = (const uint2*)xh;   // row stride = 16 uint2
    uint2* Mw = (uint2*)M;
    for (int base = wid * 2; base < N_NODES; base += stride * 2) {
        int r1ok = base + 1 < N_NODES;
        int beg0 = row_start[base],     end0 = row_start[base + 1];
        int beg1 = r1ok ? row_start[base + 1] : 0;
        int end1 = r1ok ? row_start[base + 2] : 0;
        float a0 = 0.f, a1 = 0.f, a2 = 0.f, a3 = 0.f;
        float b0 = 0.f, b1 = 0.f, b2 = 0.f, b3 = 0.f;
        int j0 = beg0 + slot, j1 = beg1 + slot;
        // ---- dual main loop: 8 load instr in flight (32 rows)
        while (j0 + 12 < end0 && j1 + 12 < end1) {
            int s00 = adj[j0], s01 = adj[j0 + 4], s02 = adj[j0 + 8], s03 = adj[j0 + 12];
            int s10 = adj[j1], s11 = adj[j1 + 4], s12 = adj[j1 + 8], s13 = adj[j1 + 12];
            uint2 u0 = xw[(size_t)s00 * 16 + c];
            uint2 u1 = xw[(size_t)s01 * 16 + c];
            uint2 u2 = xw[(size_t)s02 * 16 + c];
            uint2 u3 = xw[(size_t)s03 * 16 + c];
            uint2 v0 = xw[(size_t)s10 * 16 + c];
            uint2 v1 = xw[(size_t)s11 * 16 + c];
            uint2 v2 = xw[(size_t)s12 * 16 + c];
            uint2 v3 = xw[(size_t)s13 * 16 + c];
            a0 += bflo(u0.x) + bflo(u1.x) + bflo(u2.x) + bflo(u3.x);
            a1 += bfhi(u0.x) + bfhi(u1.x) + bfhi(u2.x) + bfhi(u3.x);
            a2 += bflo(u0.y) + bflo(u1.y) + bflo(u2.y) + bflo(u3.y);
            a3 += bfhi(u0.y) + bfhi(u1.y) + bfhi(u2.y) + bfhi(u3.y);
            b0 += bflo(v0.x) + bflo(v1.x) + bflo(v2.x) + bflo(v3.x);
            b1 += bfhi(v0.x) + bfhi(v1.x) + bfhi(v2.x) + bfhi(v3.x);
            b2 += bflo(v0.y) + bflo(v1.y) + bflo(v2.y) + bflo(v3.y);
            b3 += bfhi(v0.y) + bfhi(v1.y) + bfhi(v2.y) + bfhi(v3.y);
            j0 += 16; j1 += 16;
        }
        // ---- row0 tail
        for (; j0 + 12 < end0; j0 += 16) {
            int s0 = adj[j0], s1 = adj[j0 + 4], s2 = adj[j0 + 8], s3 = adj[j0 + 12];
            uint2 u0 = xw[(size_t)s0 * 16 + c];
            uint2 u1 = xw[(size_t)s1 * 16 + c];
            uint2 u2 = xw[(size_t)s2 * 16 + c];
            uint2 u3 = xw[(size_t)s3 * 16 + c];
            a0 += bflo(u0.x) + bflo(u1.x) + bflo(u2.x) + bflo(u3.x);
            a1 += bfhi(u0.x) + bfhi(u1.x) + bfhi(u2.x) + bfhi(u3.x);
            a2 += bflo(u0.y) + bflo(u1.y) + bflo(u2.y) + bflo(u3.y);
            a3 += bfhi(u0.y) + bfhi(u1.y) + bfhi(u2.y) + bfhi(u3.y);
        }
        for (; j0 < end0; j0 += 4) {
            uint2 v = xw[(size_t)adj[j0] * 16 + c];
            a0 += bflo(v.x); a1 += bfhi(v.x);
            a2 += bflo(v.y); a3 += bfhi(v.y);
        }
        // ---- row1 tail
        for (; j1 + 12 < end1; j1 += 16) {
            int s0 = adj[j1], s1 = adj[j1 + 4], s2 = adj[j1 + 8], s3 = adj[j1 + 12];
            uint2 u0 = xw[(size_t)s0 * 16 + c];
            uint2 u1 = xw[(size_t)s1 * 16 + c];
            uint2 u2 = xw[(size_t)s2 * 16 + c];
            uint2 u3 = xw[(size_t)s3 * 16 + c];
            b0 += bflo(u0.x) + bflo(u1.x) + bflo(u2.x) + bflo(u3.x);
            b1 += bfhi(u0.x) + bfhi(u1.x) + bfhi(u2.x) + bfhi(u3.x);
            b2 += bflo(u0.y) + bflo(u1.y) + bflo(u2.y) + bflo(u3.y);
            b3 += bfhi(u0.y) + bfhi(u1.y) + bfhi(u2.y) + bfhi(u3.y);
        }
        for (; j1 < end1; j1 += 4) {
            uint2 v = xw[(size_t)adj[j1] * 16 + c];
            b0 += bflo(v.x); b1 += bfhi(v.x);
            b2 += bflo(v.y); b3 += bfhi(v.y);
        }
        // ---- reduce + write both rows
        a0 += __shfl_xor(a0, 16); a0 += __shfl_xor(a0, 32);
        a1 += __shfl_xor(a1, 16); a1 += __shfl_xor(a1, 32);
        a2 += __shfl_xor(a2, 16); a2 += __shfl_xor(a2, 32);
        a3 += __shfl_xor(a3, 16); a3 += __shfl_xor(a3, 32);
        b0 += __shfl_xor(b0, 16); b0 += __shfl_xor(b0, 32);
        b1 += __shfl_xor(b1, 16); b1 += __shfl_xor(b1, 32);
        b2 += __shfl_xor(b2, 16); b2 += __shfl_xor(b2, 32);
        b3 += __shfl_xor(b3, 16); b3 += __shfl_xor(b3, 32);
        if (slot == 0) {
            float inv = 1.0f / fmaxf((float)(end0 - beg0), 1.0f);
            uint2 p;
            p.x = (unsigned)f2bf(a0 * inv) | ((unsigned)f2bf(a1 * inv) << 16);
            p.y = (unsigned)f2bf(a2 * inv) | ((unsigned)f2bf(a3 * inv) << 16);
            Mw[(size_t)base * 16 + c] = p;
        } else if (slot == 1 && r1ok) {
            float inv = 1.0f / fmaxf((float)(end1 - beg1), 1.0f);
            uint2 p;
            p.x = (unsigned)f2bf(b0 * inv) | ((unsigned)f2bf(b1 * inv) << 16);
            p.y = (unsigned)f2bf(b2 * inv) | ((unsigned)f2bf(b3 * inv) << 16);
            Mw[(size_t)(base + 1) * 16 + c] = p;
        }
    }
}

// ---------------------------------------------------------------- MFMA GEMM
// H[N,64] = Am @ Wl^T + As @ Wr^T + bias (bf16 in, fp32 acc, bf16 out).
// Weights come pre-converted in B-frag order: 16 vector b128 loads replace
// 128 scalar fp32 loads per lane.
__global__ void gemm_kernel(const unsigned short* __restrict__ Am,
                            const unsigned short* __restrict__ As,
                            const unsigned short* __restrict__ Wf,
                            const float* __restrict__ bias,
                            unsigned short* __restrict__ H,
                            int relu) {
    int lane = threadIdx.x & 63;
    int m = lane & 15, quad = lane >> 4;

    bf16x8 wf[2][2][4];   // [matrix][kstep][ctile]
    #pragma unroll
    for (int mat = 0; mat < 2; ++mat)
        #pragma unroll
        for (int ks = 0; ks < 2; ++ks)
            #pragma unroll
            for (int ct = 0; ct < 4; ++ct)
                wf[mat][ks][ct] = *(const bf16x8*)(Wf + ((((mat * 2 + ks) * 4) + ct) << 9) + lane * 8);
    float bv[4];
    #pragma unroll
    for (int ct = 0; ct < 4; ++ct) bv[ct] = bias[ct * 16 + m];

    int wpb = blockDim.x >> 6;
    int wid = blockIdx.x * wpb + (threadIdx.x >> 6);
    int stride = gridDim.x * wpb;
    const int NT = N_NODES / 16;
    for (int t = wid; t < NT; t += stride) {
        f32x4 acc[4] = {{0,0,0,0},{0,0,0,0},{0,0,0,0},{0,0,0,0}};
        size_t rowbase = ((size_t)t * 16 + m) * HID;
        #pragma unroll
        for (int ks = 0; ks < 2; ++ks) {
            bf16x8 a0 = *(const bf16x8*)(Am + rowbase + ks * 32 + quad * 8);
            bf16x8 a1 = *(const bf16x8*)(As + rowbase + ks * 32 + quad * 8);
            #pragma unroll
            for (int ct = 0; ct < 4; ++ct) {
                acc[ct] = __builtin_amdgcn_mfma_f32_16x16x32_bf16(a0, wf[0][ks][ct], acc[ct], 0, 0, 0);
                acc[ct] = __builtin_amdgcn_mfma_f32_16x16x32_bf16(a1, wf[1][ks][ct], acc[ct], 0, 0, 0);
            }
        }
        #pragma unroll
        for (int ct = 0; ct < 4; ++ct) {
            #pragma unroll
            for (int r = 0; r < 4; ++r) {
                float v = acc[ct][r] + bv[ct];
                if (relu) v = fmaxf(v, 0.f);
                H[((size_t)t * 16 + quad * 4 + r) * HID + ct * 16 + m] = f2bf(v);
            }
        }
    }
}

// ---------------------------------------------------------------- edge dot (bf16)
// 8 lanes per 2 consecutive edges: 4 uint4 loads/lane in flight,
// coalesced float2 output write. (At the ~3.7 TB/s L2-miss-path ceiling.)
__global__ void edge_dot_kernel(const int* __restrict__ src,
                                const int* __restrict__ dst,
                                const unsigned short* __restrict__ h,
                                float* __restrict__ out) {
    int t = blockIdx.x * blockDim.x + threadIdx.x;
    int g = t >> 3;                 // edge-pair group
    int c = t & 7;
    int e0 = g * 2;
    if (e0 >= N_EDGES) return;
    int a0 = src[e0],     b0 = dst[e0];
    int a1 = src[e0 + 1], b1 = dst[e0 + 1];
    const uint4* h4 = reinterpret_cast<const uint4*>(h);
    uint4 va0 = h4[(size_t)a0 * 8 + c];
    uint4 vb0 = h4[(size_t)b0 * 8 + c];
    uint4 va1 = h4[(size_t)a1 * 8 + c];
    uint4 vb1 = h4[(size_t)b1 * 8 + c];
    float p0 = bflo(va0.x) * bflo(vb0.x) + bfhi(va0.x) * bfhi(vb0.x)
             + bflo(va0.y) * bflo(vb0.y) + bfhi(va0.y) * bfhi(vb0.y)
             + bflo(va0.z) * bflo(vb0.z) + bfhi(va0.z) * bfhi(vb0.z)
             + bflo(va0.w) * bflo(vb0.w) + bfhi(va0.w) * bfhi(vb0.w);
    float p1 = bflo(va1.x) * bflo(vb1.x) + bfhi(va1.x) * bfhi(vb1.x)
             + bflo(va1.y) * bflo(vb1.y) + bfhi(va1.y) * bfhi(vb1.y)
             + bflo(va1.z) * bflo(vb1.z) + bfhi(va1.z) * bfhi(vb1.z)
             + bflo(va1.w) * bflo(vb1.w) + bfhi(va1.w) * bfhi(vb1.w);
    p0 += __shfl_xor(p0, 1); p0 += __shfl_xor(p0, 2); p0 += __shfl_xor(p0, 4);
    p1 += __shfl_xor(p1, 1); p1 += __shfl_xor(p1, 2); p1 += __shfl_xor(p1, 4);
    if (c == 0) reinterpret_cast<float2*>(out)[g] = make_float2(p0, p1);
}

extern "C" void kernel_launch(void* const* d_in, const int* in_sizes, int n_in,
                              void* d_out, int out_size, void* d_ws, size_t ws_size,
                              hipStream_t stream) {
    const float* emb = (const float*)d_in[0];
    const float* Wl1 = (const float*)d_in[1];
    const float* Wr1 = (const float*)d_in[2];
    const float* b1  = (const float*)d_in[3];
    const float* Wl2 = (const float*)d_in[4];
    const float* Wr2 = (const float*)d_in[5];
    const float* b2  = (const float*)d_in[6];
    const int*   nid = (const int*)d_in[7];
    const int*   ei  = (const int*)d_in[8];
    const int* esrc = ei;
    const int* edst = ei + N_EDGES;
    float* out = (float*)d_out;

    const size_t NH = (size_t)N_NODES * HID;   // 6.4M elements
    unsigned short* xh  = (unsigned short*)d_ws;          // [N,64] bf16
    unsigned short* h1h = xh + NH;                        // [N,64] bf16
    unsigned short* h2h = h1h + NH;                       // [N,64] bf16
    unsigned short* M   = h2h + NH;                       // [N,64] bf16 (mean agg)
    unsigned short* wf1 = M + NH;                         // [8192] bf16 B-frags L1
    unsigned short* wf2 = wf1 + 8192;                     // [8192] bf16 B-frags L2
    int* ib        = (int*)(wf2 + 8192);                  // int region
    int* row_start = ib;                          // [N+1]
    int* adj       = ib + N_NODES + 64;           // [E]
    int* pairs     = adj + N_EDGES + 64;          // [E] packed (src<<8 | dst&255)
    int* bhist     = pairs + N_EDGES + 64;        // [NB]
    int* boff      = bhist + NB + 1;              // [NB]
    int* bcursor   = boff + NB + 1;               // [NB]

    hipMemsetAsync(bhist, 0, NB * sizeof(int), stream);

    // xh = bf16(emb[node_id]) + bucket histogram + weight-frag prep
    gather_hist_kernel<<<G_GATHER + 256 + 2, 256, 0, stream>>>(
        emb, nid, xh, edst, bhist, Wl1, Wr1, Wl2, Wr2, wf1, wf2);

    // ---- CSR build via bucket counting sort (shared by both layers)
    bucket_scan<<<1, 512, 0, stream>>>(bhist, boff, bcursor);
    bucket_scatter<<<N_EDGES / C_EPB, 256, 0, stream>>>(esrc, edst, bcursor, pairs);
    bucket_csr<<<NB, 256, 0, stream>>>(pairs, boff, bcursor, row_start, adj);

    // ---- layer 1: aggregate then MFMA GEMM (+relu)
    agg_kernel<<<2048, 256, 0, stream>>>(row_start, adj, xh, M);
    gemm_kernel<<<782, 256, 0, stream>>>(M, xh, wf1, b1, h1h, 1);

    // ---- layer 2
    agg_kernel<<<2048, 256, 0, stream>>>(row_start, adj, h1h, M);
    gemm_kernel<<<782, 256, 0, stream>>>(M, h1h, wf2, b2, h2h, 0);

    // ---- edge classifier on bf16 features
    edge_dot_kernel<<<((size_t)(N_EDGES / 2) * 8 + 255) / 256, 256, 0, stream>>>(esrc, edst, h2h, out);
}